// Round 2
// baseline (5204.691 us; speedup 1.0000x reference)
//
#include <hip/hip_runtime.h>
#include <hip/hip_bf16.h>
#include <math.h>

#define BB 16
#define TT 128
#define VV 137
#define CCH 3
#define TV (TT*VV)      // 17536
#define NCLS 226

// ---------------- BN stats: per channel (v*3+c), reduce over (b,t)=2048 ----------------
__global__ void bn_stats_kernel(const float* __restrict__ X,
                                const float* __restrict__ gamma,
                                const float* __restrict__ beta,
                                float* __restrict__ scale,
                                float* __restrict__ shift) {
  const int ch = blockIdx.x;           // 0..410
  const int v = ch / CCH, c = ch % CCH;
  const int tid = threadIdx.x;
  float s = 0.f, q = 0.f;
  for (int idx = tid; idx < BB*TT; idx += 256) {
    float x = X[(idx*VV + v)*CCH + c];
    s += x; q += x*x;
  }
  #pragma unroll
  for (int off = 32; off > 0; off >>= 1) {
    s += __shfl_down(s, off, 64);
    q += __shfl_down(q, off, 64);
  }
  __shared__ float ls[4], lq[4];
  const int wid = tid >> 6, lane = tid & 63;
  if (lane == 0) { ls[wid] = s; lq[wid] = q; }
  __syncthreads();
  if (tid == 0) {
    float S = ls[0]+ls[1]+ls[2]+ls[3];
    float Q = lq[0]+lq[1]+lq[2]+lq[3];
    const float inv_n = 1.f / (BB*TT);
    float mean = S * inv_n;
    float var = Q * inv_n - mean*mean;
    float sc = gamma[ch] * rsqrtf(var + 1e-5f);
    scale[ch] = sc;
    shift[ch] = beta[ch] - mean * sc;
  }
}

// ---------------- BN apply + transpose to [B,C,T,V] ----------------
__global__ void bn_apply_kernel(const float* __restrict__ X,
                                const float* __restrict__ scale,
                                const float* __restrict__ shift,
                                float* __restrict__ xn) {
  const int o = blockIdx.x*256 + threadIdx.x;
  if (o >= BB*CCH*TV) return;
  const int v = o % VV;
  const int t = (o / VV) % TT;
  const int c = (o / TV) % CCH;
  const int b = o / (CCH*TV);
  const int ch = v*CCH + c;
  float x = X[((b*TT + t)*VV + v)*CCH + c];
  xn[o] = x * scale[ch] + shift[ch];
}

// ---------------- weight pre-transpose: w[oc][ic][kk] -> wT[kk][ic][oc] ----------------
__global__ void wtrans_kernel(const float* __restrict__ w, float* __restrict__ wT,
                              int OC, int IC) {
  const int o = blockIdx.x*256 + threadIdx.x;
  const int total = OC*IC*9;
  if (o >= total) return;
  const int oc = o % OC;
  const int ic = (o / OC) % IC;
  const int kk = o / (OC*IC);
  wT[o] = w[(oc*IC + ic)*9 + kk];
}

// ---------------- zero a small float buffer ----------------
__global__ void zero_kernel(float* __restrict__ p, int n) {
  const int i = blockIdx.x*256 + threadIdx.x;
  if (i < n) p[i] = 0.f;
}

// ---------------- fused adjacency + graph matmul ----------------
__global__ __launch_bounds__(320)
void gmm_kernel(const float* __restrict__ X,     // raw [gb,T,V,C] (pre-offset)
                const float* __restrict__ xin,   // [gb,Cin,T,V]
                float* __restrict__ axout,       // [gb,Cin,T,V]
                int Cin) {
  __shared__ __hip_bfloat16 As[VV*VV];   // 37538 B
  __shared__ float Xs[CCH][VV];
  __shared__ float xs[16][140];
  const int bt = blockIdx.x;
  const int b = bt / TT, t = bt % TT;
  const int tid = threadIdx.x;

  for (int i = tid; i < CCH*VV; i += 320) {
    const int c = i / VV, v = i % VV;
    Xs[c][v] = X[((b*TT + t)*VV + v)*CCH + c];
  }
  __syncthreads();
  for (int e = tid; e < VV*VV; e += 320) {
    const int v = e / VV, w = e % VV;
    float d0 = Xs[0][v]-Xs[0][w];
    float d1 = Xs[1][v]-Xs[1][w];
    float d2 = Xs[2][v]-Xs[2][w];
    float dist = sqrtf(d0*d0 + d1*d1 + d2*d2);
    As[e] = __float2bfloat16(__expf(-2.f*dist));
  }
  __syncthreads();

  const bool active = (tid < 2*VV);
  const int w = (tid < VV) ? tid : tid - VV;
  const int half = (tid < VV) ? 0 : 1;
  const int chalf = Cin >> 1;
  const int c0 = half * chalf;
  const int rowb = half * 8;

  for (int cb = 0; cb < chalf; cb += 8) {
    for (int i = tid; i < 16*VV; i += 320) {
      const int r = i / VV, v = i % VV;
      const int c = (r < 8) ? (cb + r) : (chalf + cb + (r - 8));
      xs[r][v] = xin[((b*Cin + c)*TT + t)*VV + v];
    }
    __syncthreads();
    if (active) {
      float acc[8];
      #pragma unroll
      for (int cc = 0; cc < 8; ++cc) acc[cc] = 0.f;
      for (int vt = 0; vt < VV; vt += 32) {
        const int len = (VV - vt < 32) ? (VV - vt) : 32;
        for (int i0 = 0; i0 + 4 <= len; i0 += 4) {
          const float a0 = __bfloat162float(As[(vt+i0+0)*VV + w]);
          const float a1 = __bfloat162float(As[(vt+i0+1)*VV + w]);
          const float a2 = __bfloat162float(As[(vt+i0+2)*VV + w]);
          const float a3 = __bfloat162float(As[(vt+i0+3)*VV + w]);
          #pragma unroll
          for (int cc = 0; cc < 8; ++cc) {
            const float4 xq = *(const float4*)&xs[rowb+cc][vt+i0];
            acc[cc] = fmaf(a0, xq.x, acc[cc]);
            acc[cc] = fmaf(a1, xq.y, acc[cc]);
            acc[cc] = fmaf(a2, xq.z, acc[cc]);
            acc[cc] = fmaf(a3, xq.w, acc[cc]);
          }
        }
        for (int i = len & ~3; i < len; ++i) {
          const float a = __bfloat162float(As[(vt+i)*VV + w]);
          #pragma unroll
          for (int cc = 0; cc < 8; ++cc)
            acc[cc] = fmaf(a, xs[rowb+cc][vt+i], acc[cc]);
        }
      }
      #pragma unroll
      for (int cc = 0; cc < 8; ++cc)
        axout[((b*Cin + (c0 + cb + cc))*TT + t)*VV + w] = acc[cc];
    }
    __syncthreads();
  }
}

// ---------------- conv (K=9 over t) as GEMM, optional fused mean ----------------
__global__ __launch_bounds__(256)
void conv_kernel(const float* __restrict__ in,    // [gb,IC,TV]
                 const float* __restrict__ wT,    // [9,IC,OC]
                 const float* __restrict__ bias,  // [OC]
                 float* __restrict__ out,         // [gb,OC,TV]
                 float* __restrict__ mout,        // [gb,OC]
                 int IC, int OC, int relu, int fuse_mean) {
  __shared__ float in_s[8][256];
  __shared__ float w_s[8][64];
  const int tid = threadIdx.x;
  const int b = blockIdx.z;
  const int ocb = blockIdx.y * 64;
  const int n0 = blockIdx.x * 256;
  const int to = tid & 7;
  const int tn = tid >> 3;

  float acc[8][8];
  #pragma unroll
  for (int o = 0; o < 8; ++o)
    #pragma unroll
    for (int j = 0; j < 8; ++j) acc[o][j] = 0.f;

  for (int c0 = 0; c0 < IC; c0 += 8) {
    for (int kk = 0; kk < 9; ++kk) {
      const int shift = (kk - 4) * VV;
      const int g = n0 + tid + shift;
      const bool gok = (g >= 0) && (g < TV);
      #pragma unroll
      for (int r = 0; r < 8; ++r) {
        const int ic = c0 + r;
        float v = 0.f;
        if (ic < IC && gok) v = in[((size_t)b*IC + ic)*TV + g];
        in_s[r][tid] = v;
      }
      for (int i = tid; i < 512; i += 256) {
        const int ic = i >> 6, oc = i & 63;
        float v = 0.f;
        if (c0 + ic < IC) v = wT[(kk*IC + c0 + ic)*OC + ocb + oc];
        w_s[ic][oc] = v;
      }
      __syncthreads();
      #pragma unroll
      for (int ic = 0; ic < 8; ++ic) {
        const float4 wa = *(const float4*)&w_s[ic][to*8];
        const float4 wb = *(const float4*)&w_s[ic][to*8 + 4];
        const float4 xa = *(const float4*)&in_s[ic][tn*8];
        const float4 xb = *(const float4*)&in_s[ic][tn*8 + 4];
        const float wv[8] = {wa.x,wa.y,wa.z,wa.w, wb.x,wb.y,wb.z,wb.w};
        const float xv[8] = {xa.x,xa.y,xa.z,xa.w, xb.x,xb.y,xb.z,xb.w};
        #pragma unroll
        for (int o = 0; o < 8; ++o)
          #pragma unroll
          for (int j = 0; j < 8; ++j)
            acc[o][j] = fmaf(wv[o], xv[j], acc[o][j]);
      }
      __syncthreads();
    }
  }

  if (!fuse_mean) {
    #pragma unroll
    for (int o = 0; o < 8; ++o) {
      const int oc = ocb + to*8 + o;
      const float bv = bias[oc];
      #pragma unroll
      for (int j = 0; j < 8; ++j) {
        const int n = n0 + tn*8 + j;
        if (n < TV) {
          float r = acc[o][j] + bv;
          if (relu) r = fmaxf(r, 0.f);
          out[((size_t)b*OC + oc)*TV + n] = r;
        }
      }
    }
  } else {
    float* red = &in_s[0][0];   // 2048 floats, reuse
    __syncthreads();
    #pragma unroll
    for (int o = 0; o < 8; ++o) {
      const int oc = ocb + to*8 + o;
      const float bv = bias[oc];
      float s = 0.f;
      #pragma unroll
      for (int j = 0; j < 8; ++j) {
        const int n = n0 + tn*8 + j;
        if (n < TV) {
          float r = acc[o][j] + bv;
          if (relu) r = fmaxf(r, 0.f);
          s += r;
        }
      }
      red[tn*64 + to*8 + o] = s;
    }
    __syncthreads();
    if (tid < 64) {
      float s = 0.f;
      #pragma unroll 8
      for (int i = 0; i < 32; ++i) s += red[i*64 + tid];
      atomicAdd(&mout[(size_t)b*OC + ocb + tid], s * (1.f / TV));
    }
  }
}

// ---------------- FC ----------------
__global__ void fc_kernel(const float* __restrict__ mean,
                          const float* __restrict__ fcw,
                          const float* __restrict__ fcb,
                          float* __restrict__ out) {
  const int b = blockIdx.x;
  __shared__ float ms[256];
  const int tid = threadIdx.x;
  ms[tid] = mean[b*256 + tid];
  __syncthreads();
  if (tid < NCLS) {
    float acc = fcb[tid];
    for (int c = 0; c < 256; ++c) acc = fmaf(ms[c], fcw[tid*256 + c], acc);
    out[b*NCLS + tid] = acc;
  }
}

extern "C" void kernel_launch(void* const* d_in, const int* in_sizes, int n_in,
                              void* d_out, int out_size, void* d_ws, size_t ws_size,
                              hipStream_t stream) {
  const float* X    = (const float*)d_in[0];
  const float* bn_g = (const float*)d_in[1];
  const float* bn_b = (const float*)d_in[2];
  const float* w0   = (const float*)d_in[3];
  const float* cb0  = (const float*)d_in[4];
  const float* w1   = (const float*)d_in[5];
  const float* cb1  = (const float*)d_in[6];
  const float* w2   = (const float*)d_in[7];
  const float* cb2  = (const float*)d_in[8];
  const float* w3   = (const float*)d_in[9];
  const float* cb3  = (const float*)d_in[10];
  const float* fcw  = (const float*)d_in[11];
  const float* fcb  = (const float*)d_in[12];
  float* out = (float*)d_out;

  float* ws = (float*)d_ws;
  float* scale  = ws + 0;            // 512
  float* shiftb = ws + 512;          // 512
  float* meanb  = ws + 1024;         // 4096 (16*256)
  float* wT0    = ws + 5120;         // 1728
  float* wT1    = ws + 6848;         // 36864
  float* wT2    = ws + 43712;        // 73728
  float* wT3    = ws + 117440;       // 294912
  float* xn     = ws + 412352;       // 841728
  const size_t fixed = 1254080;
  const size_t perb  = 2 * (size_t)128 * TV;   // 4,489,216 floats per batch

  const size_t ws_floats = ws_size / sizeof(float);
  int g = 1;
  if (ws_floats > fixed + perb) {
    size_t gg = (ws_floats - fixed) / perb;
    g = (gg >= 16) ? 16 : (int)gg;
  }
  float* P = ws + fixed;
  float* Q = P + (size_t)g * 128 * TV;

  bn_stats_kernel<<<411, 256, 0, stream>>>(X, bn_g, bn_b, scale, shiftb);
  bn_apply_kernel<<<(BB*CCH*TV + 255)/256, 256, 0, stream>>>(X, scale, shiftb, xn);
  wtrans_kernel<<<(64*3*9   + 255)/256, 256, 0, stream>>>(w0, wT0, 64, 3);
  wtrans_kernel<<<(64*64*9  + 255)/256, 256, 0, stream>>>(w1, wT1, 64, 64);
  wtrans_kernel<<<(128*64*9 + 255)/256, 256, 0, stream>>>(w2, wT2, 128, 64);
  wtrans_kernel<<<(256*128*9+ 255)/256, 256, 0, stream>>>(w3, wT3, 256, 128);
  zero_kernel<<<16, 256, 0, stream>>>(meanb, BB*256);

  const int ntiles = (TV + 255) / 256;  // 69

  for (int b0 = 0; b0 < BB; b0 += g) {
    const int gb = (BB - b0 < g) ? (BB - b0) : g;
    const float* Xg  = X  + (size_t)b0 * TT * VV * CCH;
    const float* xng = xn + (size_t)b0 * CCH * TV;
    float* mg = meanb + (size_t)b0 * 256;

    conv_kernel<<<dim3(ntiles,1,gb), 256, 0, stream>>>(xng, wT0, cb0, P, nullptr, 3, 64, 0, 0);
    gmm_kernel<<<gb*TT, 320, 0, stream>>>(Xg, P, Q, 64);
    conv_kernel<<<dim3(ntiles,1,gb), 256, 0, stream>>>(Q, wT1, cb1, P, nullptr, 64, 64, 1, 0);
    gmm_kernel<<<gb*TT, 320, 0, stream>>>(Xg, P, Q, 64);
    conv_kernel<<<dim3(ntiles,2,gb), 256, 0, stream>>>(Q, wT2, cb2, P, nullptr, 64, 128, 1, 0);
    gmm_kernel<<<gb*TT, 320, 0, stream>>>(Xg, P, Q, 128);
    conv_kernel<<<dim3(ntiles,4,gb), 256, 0, stream>>>(Q, wT3, cb3, nullptr, mg, 128, 256, 1, 1);
  }

  fc_kernel<<<BB, 256, 0, stream>>>(meanb, fcw, fcb, out);
}